// Round 11
// baseline (176.218 us; speedup 1.0000x reference)
//
#include <hip/hip_runtime.h>

#define BATCH 512
#define GRID_N 25
#define NODES 625            // 25*25
#define BN (BATCH * NODES)   // 320000
#define NTILES (BN / 16)     // 20000
#define F 66
#define D 64
#define TPW 4                // tiles per wave
#define FC_BLOCKS (NTILES / (4 * TPW))   // 1250 blocks -> ALL co-resident (<=6/CU)

typedef short bf16x8 __attribute__((ext_vector_type(8)));  // 8 bf16 bits (4 VGPRs)
typedef float f32x4  __attribute__((ext_vector_type(4)));

// fp32 -> bf16 bits, round-to-nearest-even
__device__ __forceinline__ short f2bf(float f) {
    union { float f; unsigned u; } c; c.f = f;
    unsigned r = c.u + 0x7fffu + ((c.u >> 16) & 1u);
    return (short)(r >> 16);
}

// ---------------- Kernel A: co-resident-by-construction MFMA fc.
// h = x@Wfc^T+bfc -> hout ; u=h.Wat[0:64] ; v=h.Wat[64:128] -> workspace.
// 1250 blocks x 256 thr, 4 tiles/wave: every block resident for the whole
// kernel (no dispatch ramp) -> ~20 waves/CU sustained. B-fragments in LDS.
__global__ __launch_bounds__(256, 6) void fc_mfma(
    const float* __restrict__ x, const float* __restrict__ Wfc,
    const float* __restrict__ bfc, const float* __restrict__ Wat,
    float* __restrict__ hout, float* __restrict__ u, float* __restrict__ v)
{
    const int tid  = threadIdx.x;
    const int lane = tid & 63;
    const int wid  = tid >> 6;
    const int l15  = lane & 15;
    const int quad = lane >> 4;

    __shared__ bf16x8 Bl[12][64];     // 12,288 B

    // ---- cooperative B-fragment build: 768 entries over 256 threads ----
    // entry (t,c,ln): what lane ln needs as B[k][n=t*16+(ln&15)], K-chunk c.
#pragma unroll
    for (int e = tid; e < 768; e += 256) {
        const int ln = e & 63;
        const int tc = e >> 6;            // 0..11
        const int t  = tc / 3, c = tc - 3 * t;
        const int L  = ln & 15, Q = ln >> 4;
        const float2* wr = (const float2*)Wfc + (t * 16 + L) * 33;
        bf16x8 fr = {0, 0, 0, 0, 0, 0, 0, 0};
        if (c < 2) {
#pragma unroll
            for (int j2 = 0; j2 < 4; ++j2) {
                const float2 p = wr[c * 16 + Q * 4 + j2];
                fr[j2 * 2]     = f2bf(p.x);
                fr[j2 * 2 + 1] = f2bf(p.y);
            }
        } else if (Q == 0) {              // K-chunk 2: only k=64,65 live
            const float2 p = wr[32];
            fr[0] = f2bf(p.x); fr[1] = f2bf(p.y);
        }
        Bl[tc][ln] = fr;
    }

    // ---- epilogue constants (overlap B-build) ----
    float bft[4], wa1[4], wa2[4];
#pragma unroll
    for (int t = 0; t < 4; ++t) {
        bft[t] = bfc[t * 16 + l15];
        wa1[t] = Wat[t * 16 + l15];
        wa2[t] = Wat[64 + t * 16 + l15];
    }

    __syncthreads();    // B-fragments visible

    const int gw = blockIdx.x * 4 + wid;      // 0..4999; tiles gw*4 .. gw*4+3

#pragma unroll
    for (int t = 0; t < TPW; ++t) {
        const int tile = gw * TPW + t;
        const int bn0  = tile * 16;

        // ---- x row -> registers (8B/lane float2; TLP hides latency) ----
        const float2* rp = (const float2*)x + (size_t)tile * 528 + l15 * 33;
        float2 xb[9];
#pragma unroll
        for (int j2 = 0; j2 < 4; ++j2) {
            xb[j2]     = rp[quad * 4 + j2];               // k 0..31  (chunk 0)
            xb[4 + j2] = rp[16 + quad * 4 + j2];          // k 32..63 (chunk 1)
        }
        xb[8] = rp[32];                                   // k 64,65 (iff quad==0)

        // ---- A fragments; A[m=l15][k=quad*8+j] ----
        bf16x8 afrag[3];
#pragma unroll
        for (int c = 0; c < 2; ++c) {
            bf16x8 fr;
#pragma unroll
            for (int j2 = 0; j2 < 4; ++j2) {
                const float2 p = xb[c * 4 + j2];
                fr[j2 * 2]     = f2bf(p.x);
                fr[j2 * 2 + 1] = f2bf(p.y);
            }
            afrag[c] = fr;
        }
        {
            bf16x8 z = {0, 0, 0, 0, 0, 0, 0, 0};
            if (quad == 0) { z[0] = f2bf(xb[8].x); z[1] = f2bf(xb[8].y); }
            afrag[2] = z;
        }

        // ---- MFMA: per K-chunk, stream 4 B-frags from LDS (lane-indexed) ----
        f32x4 acc[4] = {{0,0,0,0},{0,0,0,0},{0,0,0,0},{0,0,0,0}};
#pragma unroll
        for (int c = 0; c < 3; ++c) {
            const bf16x8 b0 = Bl[c][lane];
            const bf16x8 b1 = Bl[3 + c][lane];
            const bf16x8 b2 = Bl[6 + c][lane];
            const bf16x8 b3 = Bl[9 + c][lane];
            acc[0] = __builtin_amdgcn_mfma_f32_16x16x32_bf16(afrag[c], b0, acc[0], 0, 0, 0);
            acc[1] = __builtin_amdgcn_mfma_f32_16x16x32_bf16(afrag[c], b1, acc[1], 0, 0, 0);
            acc[2] = __builtin_amdgcn_mfma_f32_16x16x32_bf16(afrag[c], b2, acc[2], 0, 0, 0);
            acc[3] = __builtin_amdgcn_mfma_f32_16x16x32_bf16(afrag[c], b3, acc[3], 0, 0, 0);
        }

        // ---- epilogue: bias, u/v partials, direct h stores (4 full lines/instr) ----
        float pu[4] = {0, 0, 0, 0}, pv[4] = {0, 0, 0, 0};
#pragma unroll
        for (int nt = 0; nt < 4; ++nt) {
#pragma unroll
            for (int r = 0; r < 4; ++r) {
                const float h = acc[nt][r] + bft[nt];
                hout[(size_t)(bn0 + quad * 4 + r) * D + nt * 16 + l15] = h;
                pu[r] = fmaf(h, wa1[nt], pu[r]);
                pv[r] = fmaf(h, wa2[nt], pv[r]);
            }
        }
#pragma unroll
        for (int off = 8; off > 0; off >>= 1) {
#pragma unroll
            for (int r = 0; r < 4; ++r) {
                pu[r] += __shfl_xor(pu[r], off, 64);
                pv[r] += __shfl_xor(pv[r], off, 64);
            }
        }
        if (l15 == 0) {     // one float4 store each
            *(float4*)(u + bn0 + quad * 4) = make_float4(pu[0], pu[1], pu[2], pu[3]);
            *(float4*)(v + bn0 + quad * 4) = make_float4(pv[0], pv[1], pv[2], pv[3]);
        }
    }
}

// ---------------- Kernel B: s[k] = leaky(u[n] + v[neigh(n,k)] + b_at); softmax over k
// wave-cooperative coalesced output via wave-private LDS
__global__ __launch_bounds__(256) void attn_kernel(
    const float* __restrict__ u, const float* __restrict__ v,
    const float* __restrict__ bat, float* __restrict__ wout)
{
    __shared__ float sw[256 * 9];
    const int tid  = threadIdx.x;
    const int lane = tid & 63;
    const int wid  = tid >> 6;
    const int bn   = blockIdx.x * 256 + tid;        // BN = 1250 * 256 exactly

    const int b   = bn / NODES;
    const int n   = bn - b * NODES;
    const int row = n / GRID_N;
    const int col = n - row * GRID_N;
    // reference's edge clamp: shift whole 3x3 window inward at the borders
    const int r0 = row + (row == 0) - (row == GRID_N - 1);
    const int c0 = col + (col == 0) - (col == GRID_N - 1);

    const float* vb = v + b * NODES;
    const float u0 = u[bn] + bat[0];

    float s[9];
#pragma unroll
    for (int k = 0; k < 9; ++k) {
        const int nr = r0 + (k / 3) - 1;
        const int nc = c0 + (k % 3) - 1;
        const float t = u0 + vb[nr * GRID_N + nc];
        s[k] = (t >= 0.0f) ? t : 0.01f * t;
    }
    float m = s[0];
#pragma unroll
    for (int k = 1; k < 9; ++k) m = fmaxf(m, s[k]);
    float sum = 0.0f;
#pragma unroll
    for (int k = 0; k < 9; ++k) { s[k] = __expf(s[k] - m); sum += s[k]; }
    const float inv = 1.0f / sum;

    float* ws = sw + wid * 576;                     // wave-private 2304 B
#pragma unroll
    for (int k = 0; k < 9; ++k) ws[lane * 9 + k] = s[k] * inv;

    // 576 floats = 144 float4 per wave, fully coalesced
    float4* dst = (float4*)(wout + (size_t)(blockIdx.x * 256 + wid * 64) * 9);
    const float4* src = (const float4*)ws;
    dst[lane]      = src[lane];
    dst[64 + lane] = src[64 + lane];
    if (lane < 16) dst[128 + lane] = src[128 + lane];
}

extern "C" void kernel_launch(void* const* d_in, const int* in_sizes, int n_in,
                              void* d_out, int out_size, void* d_ws, size_t ws_size,
                              hipStream_t stream)
{
    const float* x   = (const float*)d_in[0];
    const float* Wfc = (const float*)d_in[1];
    const float* bfc = (const float*)d_in[2];
    const float* Wat = (const float*)d_in[3];
    const float* bat = (const float*)d_in[4];

    float* hout = (float*)d_out;                       // [B, N, 64]
    float* wout = (float*)d_out + (size_t)BN * D;      // [B, N, 9]
    float* u = (float*)d_ws;                           // [B*N]
    float* v = u + BN;                                 // [B*N]

    fc_mfma<<<FC_BLOCKS, 256, 0, stream>>>(x, Wfc, bfc, Wat, hout, u, v);
    attn_kernel<<<BN / 256, 256, 0, stream>>>(u, v, bat, wout);
}